// Round 4
// baseline (933.581 us; speedup 1.0000x reference)
//
#include <hip/hip_runtime.h>

#define N_ 16384
#define E_ 262144
#define C_ 256
#define R_ 9
#define B_ 4
#define NKEY (N_ * R_)    // 147456
#define NKEY2 (2 * NKEY)  // 294912

typedef unsigned short u16;
typedef unsigned int u32;

typedef __bf16 bf16x8 __attribute__((ext_vector_type(8)));
typedef float f32x4 __attribute__((ext_vector_type(4)));
typedef unsigned short u16x8 __attribute__((ext_vector_type(8)));

__device__ __forceinline__ u16 f2bf(float x) {
  u32 u = __float_as_uint(x);
  u32 r = (u + 0x7fffu + ((u >> 16) & 1u)) >> 16;  // RNE
  return (u16)r;
}
__device__ __forceinline__ float bf2f(u16 h) {
  return __uint_as_float(((u32)h) << 16);
}

// async global->LDS, 16B per lane
__device__ __forceinline__ void gld16(const void* g, void* l) {
  __builtin_amdgcn_global_load_lds(
      (const __attribute__((address_space(1))) void*)g,
      (__attribute__((address_space(3))) void*)l, 16, 0, 0);
}

// ---------------------------------------------------------------------------
// merged prep: all four W^T matrices + both v vectors in one launch
// ---------------------------------------------------------------------------
__global__ __launch_bounds__(256) void prep_kernel(
    const float* __restrict__ b1, const float* __restrict__ a1,
    const float* __restrict__ b2, const float* __restrict__ a2,
    const float* __restrict__ b3, const float* __restrict__ a3,
    const float* __restrict__ aw3,
    const float* __restrict__ b4, const float* __restrict__ a4,
    const float* __restrict__ aw4,
    u16* __restrict__ W1, u16* __restrict__ W2,
    u16* __restrict__ W3, u16* __restrict__ W4,
    float* __restrict__ v3, float* __restrict__ v4) {
  int c = blockIdx.x, r = blockIdx.y, o = threadIdx.x;
  float s1 = 0.f, s2 = 0.f, s3 = 0.f, s4 = 0.f;
#pragma unroll
  for (int b = 0; b < B_; ++b) {
    long bi = ((long)b * C_ + c) * C_ + o;
    s1 += a1[r * B_ + b] * b1[bi];
    s2 += a2[r * B_ + b] * b2[bi];
    s3 += a3[r * B_ + b] * b3[bi];
    s4 += a4[r * B_ + b] * b4[bi];
  }
  W1[((long)r * C_ + o) * C_ + c] = f2bf(s1);
  W2[((long)r * C_ + o) * C_ + c] = f2bf(s2);
  W3[(long)o * (R_ * C_) + r * C_ + c] = f2bf(s3);
  W4[(long)o * (R_ * C_) + r * C_ + c] = f2bf(s4);

  __shared__ float red[256];
  red[o] = s3 * aw3[r * C_ + o];
  __syncthreads();
  for (int s = 128; s > 0; s >>= 1) {
    if (o < s) red[o] += red[o + s];
    __syncthreads();
  }
  float rv3 = red[0];
  __syncthreads();
  red[o] = s4 * aw4[r * C_ + o];
  __syncthreads();
  for (int s = 128; s > 0; s >>= 1) {
    if (o < s) red[o] += red[o + s];
    __syncthreads();
  }
  if (o == 0) {
    v3[r * C_ + c] = rv3;
    v4[r * C_ + c] = red[0];
  }
}

__global__ void cvt_bf16_kernel(const float* __restrict__ in, u16* __restrict__ out) {
  long i = ((long)blockIdx.x * 256 + threadIdx.x) * 4;
  float4 f = *(const float4*)(in + i);
  ushort4 h;
  h.x = f2bf(f.x); h.y = f2bf(f.y); h.z = f2bf(f.z); h.w = f2bf(f.w);
  *(ushort4*)(out + i) = h;
}

// ---------------------------------------------------------------------------
// Fused Y GEMM 128x128x32: z<R uses (Bt0,Out0), else (Bt1,Out1). bf16 out.
// ---------------------------------------------------------------------------
#define BM 128
#define BN 128
#define BK 32

__global__ __launch_bounds__(256) void gemmY_kernel(
    const u16* __restrict__ A, int lda,
    const u16* __restrict__ Bt0, const u16* __restrict__ Bt1, long bBatch, int K,
    u16* __restrict__ Out0, u16* __restrict__ Out1, long cBatch, int ldc) {
  __shared__ __attribute__((aligned(16))) u16 As[BM * BK];
  __shared__ __attribute__((aligned(16))) u16 Bs[BN * BK];

  const int t = threadIdx.x;
  const int m0 = blockIdx.x * BM;
  const int n0 = blockIdx.y * BN;
  const int zb = blockIdx.z;
  const long z = (zb < R_) ? zb : zb - R_;
  const u16* Bt = (zb < R_) ? Bt0 : Bt1;
  u16* Out = (zb < R_) ? Out0 : Out1;

  const int sr = t >> 2;
  const int sk = (t & 3) * 8;

  const int w = t >> 6, lane = t & 63;
  const int wm = (w >> 1) * 64, wn = (w & 1) * 64;
  const int lr = lane & 15;
  const int lk = (lane >> 4) * 8;

  f32x4 acc[4][4];
#pragma unroll
  for (int i = 0; i < 4; ++i)
#pragma unroll
    for (int j = 0; j < 4; ++j) acc[i][j] = (f32x4){0.f, 0.f, 0.f, 0.f};

  const u16* aR = A + (long)(m0 + sr) * lda + sk;
  const u16* bR = Bt + z * bBatch + (long)(n0 + sr) * K + sk;
  const long aStep = 64L * lda;
  const long bStep = 64L * K;

  u16* aD0 = &As[t * 8];
  u16* aD1 = &As[2048 + t * 8];
  u16* bD0 = &Bs[t * 8];
  u16* bD1 = &Bs[2048 + t * 8];

  for (int k0 = 0; k0 < K; k0 += BK) {
    gld16(aR, aD0);
    gld16(aR + aStep, aD1);
    gld16(bR, bD0);
    gld16(bR + bStep, bD1);
    aR += BK;
    bR += BK;
    __syncthreads();

    bf16x8 af[4], bg[4];
#pragma unroll
    for (int mi = 0; mi < 4; ++mi)
      af[mi] = *(const bf16x8*)&As[(wm + mi * 16 + lr) * BK + lk];
#pragma unroll
    for (int ni = 0; ni < 4; ++ni)
      bg[ni] = *(const bf16x8*)&Bs[(wn + ni * 16 + lr) * BK + lk];
#pragma unroll
    for (int mi = 0; mi < 4; ++mi)
#pragma unroll
      for (int ni = 0; ni < 4; ++ni)
        acc[mi][ni] = __builtin_amdgcn_mfma_f32_16x16x32_bf16(af[mi], bg[ni], acc[mi][ni], 0, 0, 0);

    __syncthreads();
  }

  long base = z * cBatch;
#pragma unroll
  for (int mi = 0; mi < 4; ++mi) {
    int rowb = m0 + wm + mi * 16 + ((lane >> 4) * 4);
#pragma unroll
    for (int ni = 0; ni < 4; ++ni) {
      int col = n0 + wn + ni * 16 + lr;
      f32x4 c = acc[mi][ni];
#pragma unroll
      for (int i = 0; i < 4; ++i) {
        long idx = base + (long)(rowb + i) * ldc + col;
        Out[idx] = f2bf(c[i]);
      }
    }
  }
}

// ---------------------------------------------------------------------------
// GEMM 64x128x32 for the skinny K=2304 agg GEMMs: grid 512 = 2 blocks/CU
// OMODE: 3 = node = nf + 0.5*dv[row]*acc, 4 = node += 0.5*dv[row]*acc
// ---------------------------------------------------------------------------
template <int OMODE>
__global__ __launch_bounds__(256) void gemm64_kernel(
    const u16* __restrict__ A, int lda,
    const u16* __restrict__ Bt, int K,
    float* __restrict__ Out, int ldc,
    const float* __restrict__ nf, const float* __restrict__ dv) {
  __shared__ __attribute__((aligned(16))) u16 As[64 * BK];
  __shared__ __attribute__((aligned(16))) u16 Bs[BN * BK];

  const int t = threadIdx.x;
  const int m0 = blockIdx.x * 64;
  const int n0 = blockIdx.y * BN;

  const int sr = t >> 2;
  const int sk = (t & 3) * 8;

  const int w = t >> 6, lane = t & 63;
  const int wm = (w >> 1) * 32, wn = (w & 1) * 64;
  const int lr = lane & 15;
  const int lk = (lane >> 4) * 8;

  f32x4 acc[2][4];
#pragma unroll
  for (int i = 0; i < 2; ++i)
#pragma unroll
    for (int j = 0; j < 4; ++j) acc[i][j] = (f32x4){0.f, 0.f, 0.f, 0.f};

  const u16* aR = A + (long)(m0 + sr) * lda + sk;
  const u16* bR = Bt + (long)(n0 + sr) * K + sk;
  const long bStep = 64L * K;

  u16* aD = &As[t * 8];
  u16* bD0 = &Bs[t * 8];
  u16* bD1 = &Bs[2048 + t * 8];

  for (int k0 = 0; k0 < K; k0 += BK) {
    gld16(aR, aD);
    gld16(bR, bD0);
    gld16(bR + bStep, bD1);
    aR += BK;
    bR += BK;
    __syncthreads();

    bf16x8 af[2], bg[4];
#pragma unroll
    for (int mi = 0; mi < 2; ++mi)
      af[mi] = *(const bf16x8*)&As[(wm + mi * 16 + lr) * BK + lk];
#pragma unroll
    for (int ni = 0; ni < 4; ++ni)
      bg[ni] = *(const bf16x8*)&Bs[(wn + ni * 16 + lr) * BK + lk];
#pragma unroll
    for (int mi = 0; mi < 2; ++mi)
#pragma unroll
      for (int ni = 0; ni < 4; ++ni)
        acc[mi][ni] = __builtin_amdgcn_mfma_f32_16x16x32_bf16(af[mi], bg[ni], acc[mi][ni], 0, 0, 0);

    __syncthreads();
  }

#pragma unroll
  for (int mi = 0; mi < 2; ++mi) {
    int rowb = m0 + wm + mi * 16 + ((lane >> 4) * 4);
    float fs[4];
#pragma unroll
    for (int i = 0; i < 4; ++i) fs[i] = 0.5f * dv[rowb + i];
#pragma unroll
    for (int ni = 0; ni < 4; ++ni) {
      int col = n0 + wn + ni * 16 + lr;
      f32x4 c = acc[mi][ni];
#pragma unroll
      for (int i = 0; i < 4; ++i) {
        long idx = (long)(rowb + i) * ldc + col;
        if (OMODE == 3) Out[idx] = nf[idx] + fs[i] * c[i];
        else Out[idx] += fs[i] * c[i];
      }
    }
  }
}

// ---------------------------------------------------------------------------
// rel_emb + fused scores + merged histogram.
// TWO edges per 32-lane group: all long-latency loads (8 index, 4 row
// gathers, 4 ef loads) issue before any compute -> 2x memory parallelism.
// ---------------------------------------------------------------------------
__global__ __launch_bounds__(256) void relemb_kernel(
    const float* __restrict__ ef, const u16* __restrict__ Ysub,
    const u16* __restrict__ Yobj, const int* __restrict__ src,
    const int* __restrict__ dst, const int* __restrict__ et,
    const int* __restrict__ eti, const float* __restrict__ vS,
    const float* __restrict__ abS, const float* __restrict__ vO,
    const float* __restrict__ abO, float* __restrict__ rel,
    float* __restrict__ scoreS, float* __restrict__ scoreO,
    int* __restrict__ cnt) {
  int g = threadIdx.x >> 5;
  int h = threadIdx.x & 31;
  int c = h * 8;
  int e0 = blockIdx.x * 16 + g * 2;
  int e1 = e0 + 1;

  int sn0 = src[e0], dn0 = dst[e0], tf0 = et[e0], ti0 = eti[e0];
  int sn1 = src[e1], dn1 = dst[e1], tf1 = et[e1], ti1 = eti[e1];

  u16x8 ys0 = *(const u16x8*)(Ysub + ((long)tf0 * N_ + sn0) * C_ + c);
  u16x8 yo0 = *(const u16x8*)(Yobj + ((long)ti0 * N_ + dn0) * C_ + c);
  u16x8 ys1 = *(const u16x8*)(Ysub + ((long)tf1 * N_ + sn1) * C_ + c);
  u16x8 yo1 = *(const u16x8*)(Yobj + ((long)ti1 * N_ + dn1) * C_ + c);

  long ei0 = (long)e0 * C_ + c;
  long ei1 = (long)e1 * C_ + c;
  f32x4 f00 = __builtin_nontemporal_load((const f32x4*)(ef + ei0));
  f32x4 f01 = __builtin_nontemporal_load((const f32x4*)(ef + ei0 + 4));
  f32x4 f10 = __builtin_nontemporal_load((const f32x4*)(ef + ei1));
  f32x4 f11 = __builtin_nontemporal_load((const f32x4*)(ef + ei1 + 4));

  // ---- edge 0 ----
  float a0 = f00[0] + 0.5f * (bf2f(ys0[0]) + bf2f(yo0[0]));
  float a1 = f00[1] + 0.5f * (bf2f(ys0[1]) + bf2f(yo0[1]));
  float a2 = f00[2] + 0.5f * (bf2f(ys0[2]) + bf2f(yo0[2]));
  float a3 = f00[3] + 0.5f * (bf2f(ys0[3]) + bf2f(yo0[3]));
  float a4 = f01[0] + 0.5f * (bf2f(ys0[4]) + bf2f(yo0[4]));
  float a5 = f01[1] + 0.5f * (bf2f(ys0[5]) + bf2f(yo0[5]));
  float a6 = f01[2] + 0.5f * (bf2f(ys0[6]) + bf2f(yo0[6]));
  float a7 = f01[3] + 0.5f * (bf2f(ys0[7]) + bf2f(yo0[7]));
  *(f32x4*)(rel + ei0) = (f32x4){a0, a1, a2, a3};
  *(f32x4*)(rel + ei0 + 4) = (f32x4){a4, a5, a6, a7};

  // ---- edge 1 ----
  float b0 = f10[0] + 0.5f * (bf2f(ys1[0]) + bf2f(yo1[0]));
  float b1 = f10[1] + 0.5f * (bf2f(ys1[1]) + bf2f(yo1[1]));
  float b2 = f10[2] + 0.5f * (bf2f(ys1[2]) + bf2f(yo1[2]));
  float b3 = f10[3] + 0.5f * (bf2f(ys1[3]) + bf2f(yo1[3]));
  float b4 = f11[0] + 0.5f * (bf2f(ys1[4]) + bf2f(yo1[4]));
  float b5 = f11[1] + 0.5f * (bf2f(ys1[5]) + bf2f(yo1[5]));
  float b6 = f11[2] + 0.5f * (bf2f(ys1[6]) + bf2f(yo1[6]));
  float b7 = f11[3] + 0.5f * (bf2f(ys1[7]) + bf2f(yo1[7]));
  *(f32x4*)(rel + ei1) = (f32x4){b0, b1, b2, b3};
  *(f32x4*)(rel + ei1 + 4) = (f32x4){b4, b5, b6, b7};

  // ---- dots (v tables are L1-resident: 9 KB each) ----
  float4 w0, w1;
  w0 = *(const float4*)(vS + ti0 * C_ + c);
  w1 = *(const float4*)(vS + ti0 * C_ + c + 4);
  float pS0 = a0 * w0.x + a1 * w0.y + a2 * w0.z + a3 * w0.w +
              a4 * w1.x + a5 * w1.y + a6 * w1.z + a7 * w1.w;
  w0 = *(const float4*)(vO + tf0 * C_ + c);
  w1 = *(const float4*)(vO + tf0 * C_ + c + 4);
  float pO0 = a0 * w0.x + a1 * w0.y + a2 * w0.z + a3 * w0.w +
              a4 * w1.x + a5 * w1.y + a6 * w1.z + a7 * w1.w;
  w0 = *(const float4*)(vS + ti1 * C_ + c);
  w1 = *(const float4*)(vS + ti1 * C_ + c + 4);
  float pS1 = b0 * w0.x + b1 * w0.y + b2 * w0.z + b3 * w0.w +
              b4 * w1.x + b5 * w1.y + b6 * w1.z + b7 * w1.w;
  w0 = *(const float4*)(vO + tf1 * C_ + c);
  w1 = *(const float4*)(vO + tf1 * C_ + c + 4);
  float pO1 = b0 * w0.x + b1 * w0.y + b2 * w0.z + b3 * w0.w +
              b4 * w1.x + b5 * w1.y + b6 * w1.z + b7 * w1.w;

#pragma unroll
  for (int off = 16; off > 0; off >>= 1) {
    pS0 += __shfl_xor(pS0, off);
    pO0 += __shfl_xor(pO0, off);
    pS1 += __shfl_xor(pS1, off);
    pO1 += __shfl_xor(pO1, off);
  }
  if (h == 0) {
    float sS = pS0 + abS[ti0];
    sS = sS > 0.f ? sS : 0.01f * sS;
    scoreS[e0] = sS;
    atomicAdd(&cnt[sn0 * R_ + ti0], 1);
    float sO = pO0 + abO[tf0];
    sO = sO > 0.f ? sO : 0.01f * sO;
    scoreO[e0] = sO;
    atomicAdd(&cnt[NKEY + dn0 * R_ + tf0], 1);

    sS = pS1 + abS[ti1];
    sS = sS > 0.f ? sS : 0.01f * sS;
    scoreS[e1] = sS;
    atomicAdd(&cnt[sn1 * R_ + ti1], 1);
    sO = pO1 + abO[tf1];
    sO = sO > 0.f ? sO : 0.01f * sO;
    scoreO[e1] = sO;
    atomicAdd(&cnt[NKEY + dn1 * R_ + tf1], 1);
  }
}

__global__ __launch_bounds__(256) void div_kernel(const int* __restrict__ cnt,
                                                  float* __restrict__ divS,
                                                  float* __restrict__ divO) {
  int n = blockIdx.x * 256 + threadIdx.x;
  int ds = 0, dq = 0;
#pragma unroll
  for (int r = 0; r < R_; ++r) {
    ds += (cnt[n * R_ + r] > 0);
    dq += (cnt[NKEY + n * R_ + r] > 0);
  }
  divS[n] = ds ? 1.f / (float)ds : 1.f;
  divO[n] = dq ? 1.f / (float)dq : 1.f;
}

// ---------------------------------------------------------------------------
// merged hierarchical exclusive scan over NKEY2=294912 counts (288 x 1024)
// ---------------------------------------------------------------------------
__global__ __launch_bounds__(256) void scan1_kernel(const int* __restrict__ cnt,
                                                    int* __restrict__ offs,
                                                    int* __restrict__ part) {
  __shared__ int lds[256];
  int b = blockIdx.x, t = threadIdx.x;
  int base = b * 1024 + t * 4;
  int4 v = *(const int4*)(cnt + base);
  int tsum = v.x + v.y + v.z + v.w;
  lds[t] = tsum;
  __syncthreads();
  for (int d = 1; d < 256; d <<= 1) {
    int x = (t >= d) ? lds[t - d] : 0;
    __syncthreads();
    lds[t] += x;
    __syncthreads();
  }
  int run = (t == 0) ? 0 : lds[t - 1];
  int4 o;
  o.x = run;
  o.y = run + v.x;
  o.z = o.y + v.y;
  o.w = o.z + v.z;
  *(int4*)(offs + base) = o;
  if (t == 255) part[b] = lds[255];
}

__global__ __launch_bounds__(512) void scan2_kernel(int* __restrict__ part) {
  __shared__ int lds[512];
  int t = threadIdx.x;
  lds[t] = (t < 288) ? part[t] : 0;
  __syncthreads();
  for (int d = 1; d < 512; d <<= 1) {
    int x = (t >= d) ? lds[t - d] : 0;
    __syncthreads();
    lds[t] += x;
    __syncthreads();
  }
  if (t < 288) part[t] = (t == 0) ? 0 : lds[t - 1];
}

__global__ __launch_bounds__(256) void scan3_kernel(const int* __restrict__ part,
                                                    int* __restrict__ offs,
                                                    int* __restrict__ cursor) {
  int i = blockIdx.x * 256 + threadIdx.x;  // grid 1152
  int v = offs[i] + part[i >> 10];
  offs[i] = v;
  cursor[i] = v;
}

// one pass: scatter edge into both branches' key lists
__global__ __launch_bounds__(256) void scatter_kernel(
    const int* __restrict__ et, const int* __restrict__ eti,
    const int* __restrict__ src, const int* __restrict__ dst,
    int* __restrict__ cursor, int* __restrict__ order) {
  int e = blockIdx.x * 256 + threadIdx.x;
  int kS = src[e] * R_ + eti[e];
  int kO = NKEY + dst[e] * R_ + et[e];
  order[atomicAdd(&cursor[kS], 1)] = e;
  order[atomicAdd(&cursor[kO], 1)] = e;
}

// ---------------------------------------------------------------------------
// one wave per key, both branches in one launch.
// ---------------------------------------------------------------------------
__global__ __launch_bounds__(256) void zgather_kernel(
    const float* __restrict__ rel, const float* __restrict__ scoreS,
    const float* __restrict__ scoreO, const int* __restrict__ order,
    const int* __restrict__ offs, const int* __restrict__ cnt,
    u16* __restrict__ zS, u16* __restrict__ zO) {
  int key = blockIdx.x * 4 + (threadIdx.x >> 6);
  int lane = threadIdx.x & 63;
  int c = lane * 4;
  int len = cnt[key];
  int start = offs[key];
  const float* score = scoreS;
  u16* z = zS;
  int k2 = key;
  if (key >= NKEY) { score = scoreO; z = zO; k2 = key - NKEY; }

  float ax = 0.f, ay = 0.f, az = 0.f, aw = 0.f;
  if (len == 1) {
    int e = order[start];
    float4 x = *(const float4*)(rel + (long)e * C_ + c);
    ax = x.x; ay = x.y; az = x.z; aw = x.w;
  } else if (len > 1 && len <= 64) {
    int e_l = 0;
    float s_l = 0.f;
    if (lane < len) {
      e_l = order[start + lane];
      s_l = __expf(score[e_l]);
    }
    float den = s_l;
#pragma unroll
    for (int off = 32; off > 0; off >>= 1) den += __shfl_xor(den, off);
    float inv = 1.f / den;
    int i = 0;
    for (; i + 2 <= len; i += 2) {
      int e0 = __shfl(e_l, i);
      int e1 = __shfl(e_l, i + 1);
      float a0 = __shfl(s_l, i) * inv;
      float a1 = __shfl(s_l, i + 1) * inv;
      float4 x0 = *(const float4*)(rel + (long)e0 * C_ + c);
      float4 x1 = *(const float4*)(rel + (long)e1 * C_ + c);
      ax += a0 * x0.x + a1 * x1.x;
      ay += a0 * x0.y + a1 * x1.y;
      az += a0 * x0.z + a1 * x1.z;
      aw += a0 * x0.w + a1 * x1.w;
    }
    if (i < len) {
      int e0 = __shfl(e_l, i);
      float a0 = __shfl(s_l, i) * inv;
      float4 x0 = *(const float4*)(rel + (long)e0 * C_ + c);
      ax += a0 * x0.x;
      ay += a0 * x0.y;
      az += a0 * x0.z;
      aw += a0 * x0.w;
    }
  } else if (len > 64) {
    float den = 0.f;
    for (int i = 0; i < len; ++i) {
      int e = order[start + i];
      float ex = __expf(score[e]);
      den += ex;
      float4 x = *(const float4*)(rel + (long)e * C_ + c);
      ax += ex * x.x; ay += ex * x.y; az += ex * x.z; aw += ex * x.w;
    }
    float inv = 1.f / den;
    ax *= inv; ay *= inv; az *= inv; aw *= inv;
  }
  int n = k2 / R_, r = k2 - n * R_;
  ushort4 h;
  h.x = f2bf(ax); h.y = f2bf(ay); h.z = f2bf(az); h.w = f2bf(aw);
  *(ushort4*)(z + (long)n * (R_ * C_) + r * C_ + c) = h;
}

// ---------------------------------------------------------------------------
extern "C" void kernel_launch(void* const* d_in, const int* in_sizes, int n_in,
                              void* d_out, int out_size, void* d_ws, size_t ws_size,
                              hipStream_t stream) {
  const int* edge_index = (const int*)d_in[0];
  const float* nf = (const float*)d_in[1];
  const float* ef = (const float*)d_in[2];
  const int* et = (const int*)d_in[3];
  const int* eti = (const int*)d_in[4];
  const float* s2r_basis = (const float*)d_in[6];
  const float* s2r_att = (const float*)d_in[7];
  const float* o2r_basis = (const float*)d_in[8];
  const float* o2r_att = (const float*)d_in[9];
  const float* r2s_basis = (const float*)d_in[10];
  const float* r2s_att = (const float*)d_in[11];
  const float* r2s_aw = (const float*)d_in[12];
  const float* r2s_ab = (const float*)d_in[13];
  const float* r2o_basis = (const float*)d_in[14];
  const float* r2o_att = (const float*)d_in[15];
  const float* r2o_aw = (const float*)d_in[16];
  const float* r2o_ab = (const float*)d_in[17];

  const int* src = edge_index;
  const int* dst = edge_index + E_;

  char* ws = (char*)d_ws;
  u16* WtSub = (u16*)(ws + 0);             // 1179648
  u16* WtObj = (u16*)(ws + 1179648);
  u16* WtR2S = (u16*)(ws + 2359296);
  u16* WtR2O = (u16*)(ws + 3538944);
  float* vS = (float*)(ws + 4718592);      // 9216
  float* vO = (float*)(ws + 4727808);
  u16* nfb = (u16*)(ws + 4737024);         // 8 MB -> 13125632
  float* scoreS = (float*)(ws + 13125632);
  float* scoreO = (float*)(ws + 14174208);
  int* cnt = (int*)(ws + 15222784);        // 2*NKEY ints -> 16402432
  int* offs = (int*)(ws + 16402432);       // -> 17582080
  int* cursor = (int*)(ws + 17582080);     // -> 18761728
  int* order = (int*)(ws + 18761728);      // 2E ints -> 20858880
  int* part = (int*)(ws + 20858880);       // -> 20860928
  float* divS = (float*)(ws + 20860928);   // -> 20926464
  float* divO = (float*)(ws + 20926464);   // -> 20992000
  u16* Ysub = (u16*)(ws + 20992000);       // 75.5 MB -> 96489472
  u16* Yobj = (u16*)(ws + 96489472);       // 75.5 MB -> 171986944
  u16* zS = Ysub;  // dead after relemb
  u16* zO = Yobj;  // dead after relemb

  float* node_out = (float*)d_out;
  float* rel_out = (float*)d_out + (long)N_ * C_;

  // ---- prep (one launch) ----
  prep_kernel<<<dim3(C_, R_), 256, 0, stream>>>(
      s2r_basis, s2r_att, o2r_basis, o2r_att,
      r2s_basis, r2s_att, r2s_aw, r2o_basis, r2o_att, r2o_aw,
      WtSub, WtObj, WtR2S, WtR2O, vS, vO);
  cvt_bf16_kernel<<<(N_ * C_) / 1024, 256, 0, stream>>>(nf, nfb);
  (void)hipMemsetAsync(cnt, 0, (size_t)NKEY2 * 4, stream);

  // ---- fused Y GEMM: z<9 -> Ysub, z>=9 -> Yobj ----
  gemmY_kernel<<<dim3(N_ / BM, C_ / BN, 2 * R_), 256, 0, stream>>>(
      nfb, C_, WtSub, WtObj, (long)C_ * C_, C_, Ysub, Yobj, (long)N_ * C_, C_);

  // ---- rel_emb + scores + merged histogram ----
  relemb_kernel<<<E_ / 16, 256, 0, stream>>>(ef, Ysub, Yobj, src, dst, et, eti,
                                             vS, r2s_ab, vO, r2o_ab, rel_out,
                                             scoreS, scoreO, cnt);
  div_kernel<<<N_ / 256, 256, 0, stream>>>(cnt, divS, divO);

  // ---- merged scan + scatter + zgather (both branches) ----
  scan1_kernel<<<288, 256, 0, stream>>>(cnt, offs, part);
  scan2_kernel<<<1, 512, 0, stream>>>(part);
  scan3_kernel<<<NKEY2 / 256, 256, 0, stream>>>(part, offs, cursor);
  scatter_kernel<<<E_ / 256, 256, 0, stream>>>(et, eti, src, dst, cursor, order);
  zgather_kernel<<<NKEY2 / 4, 256, 0, stream>>>(rel_out, scoreS, scoreO, order,
                                                offs, cnt, zS, zO);

  // ---- agg GEMMs (BM=64 -> 512 blocks, 2/CU) with fused final epilogue ----
  gemm64_kernel<3><<<dim3(N_ / 64, C_ / BN), 256, 0, stream>>>(
      zS, R_ * C_, WtR2S, R_ * C_, node_out, C_, nf, divS);
  gemm64_kernel<4><<<dim3(N_ / 64, C_ / BN), 256, 0, stream>>>(
      zO, R_ * C_, WtR2O, R_ * C_, node_out, C_, nullptr, divO);

  (void)in_sizes; (void)n_in; (void)out_size; (void)ws_size;
}

// Round 5
// 907.970 us; speedup vs baseline: 1.0282x; 1.0282x over previous
//
#include <hip/hip_runtime.h>

#define N_ 16384
#define E_ 262144
#define C_ 256
#define R_ 9
#define B_ 4
#define NKEY (N_ * R_)    // 147456
#define NKEY2 (2 * NKEY)  // 294912

typedef unsigned short u16;
typedef unsigned int u32;

typedef __bf16 bf16x8 __attribute__((ext_vector_type(8)));
typedef float f32x4 __attribute__((ext_vector_type(4)));
typedef unsigned short u16x8 __attribute__((ext_vector_type(8)));

__device__ __forceinline__ u16 f2bf(float x) {
  u32 u = __float_as_uint(x);
  u32 r = (u + 0x7fffu + ((u >> 16) & 1u)) >> 16;  // RNE
  return (u16)r;
}
__device__ __forceinline__ float bf2f(u16 h) {
  return __uint_as_float(((u32)h) << 16);
}

// async global->LDS, 16B per lane
__device__ __forceinline__ void gld16(const void* g, void* l) {
  __builtin_amdgcn_global_load_lds(
      (const __attribute__((address_space(1))) void*)g,
      (__attribute__((address_space(3))) void*)l, 16, 0, 0);
}

// ---------------------------------------------------------------------------
// merged prep: all four W^T matrices + both v vectors in one launch
// ---------------------------------------------------------------------------
__global__ __launch_bounds__(256) void prep_kernel(
    const float* __restrict__ b1, const float* __restrict__ a1,
    const float* __restrict__ b2, const float* __restrict__ a2,
    const float* __restrict__ b3, const float* __restrict__ a3,
    const float* __restrict__ aw3,
    const float* __restrict__ b4, const float* __restrict__ a4,
    const float* __restrict__ aw4,
    u16* __restrict__ W1, u16* __restrict__ W2,
    u16* __restrict__ W3, u16* __restrict__ W4,
    float* __restrict__ v3, float* __restrict__ v4) {
  int c = blockIdx.x, r = blockIdx.y, o = threadIdx.x;
  float s1 = 0.f, s2 = 0.f, s3 = 0.f, s4 = 0.f;
#pragma unroll
  for (int b = 0; b < B_; ++b) {
    long bi = ((long)b * C_ + c) * C_ + o;
    s1 += a1[r * B_ + b] * b1[bi];
    s2 += a2[r * B_ + b] * b2[bi];
    s3 += a3[r * B_ + b] * b3[bi];
    s4 += a4[r * B_ + b] * b4[bi];
  }
  W1[((long)r * C_ + o) * C_ + c] = f2bf(s1);
  W2[((long)r * C_ + o) * C_ + c] = f2bf(s2);
  W3[(long)o * (R_ * C_) + r * C_ + c] = f2bf(s3);
  W4[(long)o * (R_ * C_) + r * C_ + c] = f2bf(s4);

  __shared__ float red[256];
  red[o] = s3 * aw3[r * C_ + o];
  __syncthreads();
  for (int s = 128; s > 0; s >>= 1) {
    if (o < s) red[o] += red[o + s];
    __syncthreads();
  }
  float rv3 = red[0];
  __syncthreads();
  red[o] = s4 * aw4[r * C_ + o];
  __syncthreads();
  for (int s = 128; s > 0; s >>= 1) {
    if (o < s) red[o] += red[o + s];
    __syncthreads();
  }
  if (o == 0) {
    v3[r * C_ + c] = rv3;
    v4[r * C_ + c] = red[0];
  }
}

__global__ void cvt_bf16_kernel(const float* __restrict__ in, u16* __restrict__ out) {
  long i = ((long)blockIdx.x * 256 + threadIdx.x) * 4;
  float4 f = *(const float4*)(in + i);
  ushort4 h;
  h.x = f2bf(f.x); h.y = f2bf(f.y); h.z = f2bf(f.z); h.w = f2bf(f.w);
  *(ushort4*)(out + i) = h;
}

// ---------------------------------------------------------------------------
// Fused Y GEMM 128x128x32: z<R uses (Bt0,Out0), else (Bt1,Out1). bf16 out.
// ---------------------------------------------------------------------------
#define BM 128
#define BN 128
#define BK 32

__global__ __launch_bounds__(256) void gemmY_kernel(
    const u16* __restrict__ A, int lda,
    const u16* __restrict__ Bt0, const u16* __restrict__ Bt1, long bBatch, int K,
    u16* __restrict__ Out0, u16* __restrict__ Out1, long cBatch, int ldc) {
  __shared__ __attribute__((aligned(16))) u16 As[BM * BK];
  __shared__ __attribute__((aligned(16))) u16 Bs[BN * BK];

  const int t = threadIdx.x;
  const int m0 = blockIdx.x * BM;
  const int n0 = blockIdx.y * BN;
  const int zb = blockIdx.z;
  const long z = (zb < R_) ? zb : zb - R_;
  const u16* Bt = (zb < R_) ? Bt0 : Bt1;
  u16* Out = (zb < R_) ? Out0 : Out1;

  const int sr = t >> 2;
  const int sk = (t & 3) * 8;

  const int w = t >> 6, lane = t & 63;
  const int wm = (w >> 1) * 64, wn = (w & 1) * 64;
  const int lr = lane & 15;
  const int lk = (lane >> 4) * 8;

  f32x4 acc[4][4];
#pragma unroll
  for (int i = 0; i < 4; ++i)
#pragma unroll
    for (int j = 0; j < 4; ++j) acc[i][j] = (f32x4){0.f, 0.f, 0.f, 0.f};

  const u16* aR = A + (long)(m0 + sr) * lda + sk;
  const u16* bR = Bt + z * bBatch + (long)(n0 + sr) * K + sk;
  const long aStep = 64L * lda;
  const long bStep = 64L * K;

  u16* aD0 = &As[t * 8];
  u16* aD1 = &As[2048 + t * 8];
  u16* bD0 = &Bs[t * 8];
  u16* bD1 = &Bs[2048 + t * 8];

  for (int k0 = 0; k0 < K; k0 += BK) {
    gld16(aR, aD0);
    gld16(aR + aStep, aD1);
    gld16(bR, bD0);
    gld16(bR + bStep, bD1);
    aR += BK;
    bR += BK;
    __syncthreads();

    bf16x8 af[4], bg[4];
#pragma unroll
    for (int mi = 0; mi < 4; ++mi)
      af[mi] = *(const bf16x8*)&As[(wm + mi * 16 + lr) * BK + lk];
#pragma unroll
    for (int ni = 0; ni < 4; ++ni)
      bg[ni] = *(const bf16x8*)&Bs[(wn + ni * 16 + lr) * BK + lk];
#pragma unroll
    for (int mi = 0; mi < 4; ++mi)
#pragma unroll
      for (int ni = 0; ni < 4; ++ni)
        acc[mi][ni] = __builtin_amdgcn_mfma_f32_16x16x32_bf16(af[mi], bg[ni], acc[mi][ni], 0, 0, 0);

    __syncthreads();
  }

  long base = z * cBatch;
#pragma unroll
  for (int mi = 0; mi < 4; ++mi) {
    int rowb = m0 + wm + mi * 16 + ((lane >> 4) * 4);
#pragma unroll
    for (int ni = 0; ni < 4; ++ni) {
      int col = n0 + wn + ni * 16 + lr;
      f32x4 c = acc[mi][ni];
#pragma unroll
      for (int i = 0; i < 4; ++i) {
        long idx = base + (long)(rowb + i) * ldc + col;
        Out[idx] = f2bf(c[i]);
      }
    }
  }
}

// ---------------------------------------------------------------------------
// Fused agg GEMM: both branches (K=2304 each) + final epilogue in one kernel.
// BM=64, BN=128, grid 512 blocks.  node = nf + 0.5*(divS*accS + divO*accO)
// ---------------------------------------------------------------------------
__global__ __launch_bounds__(256) void gemmAgg_kernel(
    const u16* __restrict__ AS, const u16* __restrict__ AO,
    const u16* __restrict__ BtS, const u16* __restrict__ BtO,
    float* __restrict__ Out,
    const float* __restrict__ nf,
    const float* __restrict__ divS, const float* __restrict__ divO) {
  const int K = R_ * C_;  // 2304
  __shared__ __attribute__((aligned(16))) u16 As[64 * BK];
  __shared__ __attribute__((aligned(16))) u16 Bs[BN * BK];

  const int t = threadIdx.x;
  const int m0 = blockIdx.x * 64;
  const int n0 = blockIdx.y * BN;

  const int sr = t >> 2;
  const int sk = (t & 3) * 8;

  const int w = t >> 6, lane = t & 63;
  const int wm = (w >> 1) * 32, wn = (w & 1) * 64;
  const int lr = lane & 15;
  const int lk = (lane >> 4) * 8;

  u16* aD = &As[t * 8];
  u16* bD0 = &Bs[t * 8];
  u16* bD1 = &Bs[2048 + t * 8];
  const long bStep = 64L * K;

  f32x4 accS[2][4], accO[2][4];
#pragma unroll
  for (int i = 0; i < 2; ++i)
#pragma unroll
    for (int j = 0; j < 4; ++j) {
      accS[i][j] = (f32x4){0.f, 0.f, 0.f, 0.f};
      accO[i][j] = (f32x4){0.f, 0.f, 0.f, 0.f};
    }

  // ---- pass S ----
  {
    const u16* aR = AS + (long)(m0 + sr) * K + sk;
    const u16* bR = BtS + (long)(n0 + sr) * K + sk;
    for (int k0 = 0; k0 < K; k0 += BK) {
      gld16(aR, aD);
      gld16(bR, bD0);
      gld16(bR + bStep, bD1);
      aR += BK;
      bR += BK;
      __syncthreads();
      bf16x8 af[2], bg[4];
#pragma unroll
      for (int mi = 0; mi < 2; ++mi)
        af[mi] = *(const bf16x8*)&As[(wm + mi * 16 + lr) * BK + lk];
#pragma unroll
      for (int ni = 0; ni < 4; ++ni)
        bg[ni] = *(const bf16x8*)&Bs[(wn + ni * 16 + lr) * BK + lk];
#pragma unroll
      for (int mi = 0; mi < 2; ++mi)
#pragma unroll
        for (int ni = 0; ni < 4; ++ni)
          accS[mi][ni] = __builtin_amdgcn_mfma_f32_16x16x32_bf16(af[mi], bg[ni], accS[mi][ni], 0, 0, 0);
      __syncthreads();
    }
  }
  // ---- pass O ----
  {
    const u16* aR = AO + (long)(m0 + sr) * K + sk;
    const u16* bR = BtO + (long)(n0 + sr) * K + sk;
    for (int k0 = 0; k0 < K; k0 += BK) {
      gld16(aR, aD);
      gld16(bR, bD0);
      gld16(bR + bStep, bD1);
      aR += BK;
      bR += BK;
      __syncthreads();
      bf16x8 af[2], bg[4];
#pragma unroll
      for (int mi = 0; mi < 2; ++mi)
        af[mi] = *(const bf16x8*)&As[(wm + mi * 16 + lr) * BK + lk];
#pragma unroll
      for (int ni = 0; ni < 4; ++ni)
        bg[ni] = *(const bf16x8*)&Bs[(wn + ni * 16 + lr) * BK + lk];
#pragma unroll
      for (int mi = 0; mi < 2; ++mi)
#pragma unroll
        for (int ni = 0; ni < 4; ++ni)
          accO[mi][ni] = __builtin_amdgcn_mfma_f32_16x16x32_bf16(af[mi], bg[ni], accO[mi][ni], 0, 0, 0);
      __syncthreads();
    }
  }

#pragma unroll
  for (int mi = 0; mi < 2; ++mi) {
    int rowb = m0 + wm + mi * 16 + ((lane >> 4) * 4);
    float fsS[4], fsO[4];
#pragma unroll
    for (int i = 0; i < 4; ++i) {
      fsS[i] = 0.5f * divS[rowb + i];
      fsO[i] = 0.5f * divO[rowb + i];
    }
#pragma unroll
    for (int ni = 0; ni < 4; ++ni) {
      int col = n0 + wn + ni * 16 + lr;
      f32x4 cS = accS[mi][ni];
      f32x4 cO = accO[mi][ni];
#pragma unroll
      for (int i = 0; i < 4; ++i) {
        long idx = (long)(rowb + i) * C_ + col;
        Out[idx] = nf[idx] + fsS[i] * cS[i] + fsO[i] * cO[i];
      }
    }
  }
}

// ---------------------------------------------------------------------------
// rel_emb + fused scores + merged histogram.
// TWO edges per 32-lane group, all long-latency loads issued before compute.
// (NT hint removed: R4 showed it costs +60MB FETCH, cancelling the MLP gain)
// ---------------------------------------------------------------------------
__global__ __launch_bounds__(256) void relemb_kernel(
    const float* __restrict__ ef, const u16* __restrict__ Ysub,
    const u16* __restrict__ Yobj, const int* __restrict__ src,
    const int* __restrict__ dst, const int* __restrict__ et,
    const int* __restrict__ eti, const float* __restrict__ vS,
    const float* __restrict__ abS, const float* __restrict__ vO,
    const float* __restrict__ abO, float* __restrict__ rel,
    float* __restrict__ scoreS, float* __restrict__ scoreO,
    int* __restrict__ cnt) {
  int g = threadIdx.x >> 5;
  int h = threadIdx.x & 31;
  int c = h * 8;
  int e0 = blockIdx.x * 16 + g * 2;
  int e1 = e0 + 1;

  int sn0 = src[e0], dn0 = dst[e0], tf0 = et[e0], ti0 = eti[e0];
  int sn1 = src[e1], dn1 = dst[e1], tf1 = et[e1], ti1 = eti[e1];

  u16x8 ys0 = *(const u16x8*)(Ysub + ((long)tf0 * N_ + sn0) * C_ + c);
  u16x8 yo0 = *(const u16x8*)(Yobj + ((long)ti0 * N_ + dn0) * C_ + c);
  u16x8 ys1 = *(const u16x8*)(Ysub + ((long)tf1 * N_ + sn1) * C_ + c);
  u16x8 yo1 = *(const u16x8*)(Yobj + ((long)ti1 * N_ + dn1) * C_ + c);

  long ei0 = (long)e0 * C_ + c;
  long ei1 = (long)e1 * C_ + c;
  f32x4 f00 = *(const f32x4*)(ef + ei0);
  f32x4 f01 = *(const f32x4*)(ef + ei0 + 4);
  f32x4 f10 = *(const f32x4*)(ef + ei1);
  f32x4 f11 = *(const f32x4*)(ef + ei1 + 4);

  // ---- edge 0 ----
  float a0 = f00[0] + 0.5f * (bf2f(ys0[0]) + bf2f(yo0[0]));
  float a1 = f00[1] + 0.5f * (bf2f(ys0[1]) + bf2f(yo0[1]));
  float a2 = f00[2] + 0.5f * (bf2f(ys0[2]) + bf2f(yo0[2]));
  float a3 = f00[3] + 0.5f * (bf2f(ys0[3]) + bf2f(yo0[3]));
  float a4 = f01[0] + 0.5f * (bf2f(ys0[4]) + bf2f(yo0[4]));
  float a5 = f01[1] + 0.5f * (bf2f(ys0[5]) + bf2f(yo0[5]));
  float a6 = f01[2] + 0.5f * (bf2f(ys0[6]) + bf2f(yo0[6]));
  float a7 = f01[3] + 0.5f * (bf2f(ys0[7]) + bf2f(yo0[7]));
  *(f32x4*)(rel + ei0) = (f32x4){a0, a1, a2, a3};
  *(f32x4*)(rel + ei0 + 4) = (f32x4){a4, a5, a6, a7};

  // ---- edge 1 ----
  float b0 = f10[0] + 0.5f * (bf2f(ys1[0]) + bf2f(yo1[0]));
  float b1 = f10[1] + 0.5f * (bf2f(ys1[1]) + bf2f(yo1[1]));
  float b2 = f10[2] + 0.5f * (bf2f(ys1[2]) + bf2f(yo1[2]));
  float b3 = f10[3] + 0.5f * (bf2f(ys1[3]) + bf2f(yo1[3]));
  float b4 = f11[0] + 0.5f * (bf2f(ys1[4]) + bf2f(yo1[4]));
  float b5 = f11[1] + 0.5f * (bf2f(ys1[5]) + bf2f(yo1[5]));
  float b6 = f11[2] + 0.5f * (bf2f(ys1[6]) + bf2f(yo1[6]));
  float b7 = f11[3] + 0.5f * (bf2f(ys1[7]) + bf2f(yo1[7]));
  *(f32x4*)(rel + ei1) = (f32x4){b0, b1, b2, b3};
  *(f32x4*)(rel + ei1 + 4) = (f32x4){b4, b5, b6, b7};

  // ---- dots (v tables are L1/L2-resident: 9 KB each) ----
  float4 w0, w1;
  w0 = *(const float4*)(vS + ti0 * C_ + c);
  w1 = *(const float4*)(vS + ti0 * C_ + c + 4);
  float pS0 = a0 * w0.x + a1 * w0.y + a2 * w0.z + a3 * w0.w +
              a4 * w1.x + a5 * w1.y + a6 * w1.z + a7 * w1.w;
  w0 = *(const float4*)(vO + tf0 * C_ + c);
  w1 = *(const float4*)(vO + tf0 * C_ + c + 4);
  float pO0 = a0 * w0.x + a1 * w0.y + a2 * w0.z + a3 * w0.w +
              a4 * w1.x + a5 * w1.y + a6 * w1.z + a7 * w1.w;
  w0 = *(const float4*)(vS + ti1 * C_ + c);
  w1 = *(const float4*)(vS + ti1 * C_ + c + 4);
  float pS1 = b0 * w0.x + b1 * w0.y + b2 * w0.z + b3 * w0.w +
              b4 * w1.x + b5 * w1.y + b6 * w1.z + b7 * w1.w;
  w0 = *(const float4*)(vO + tf1 * C_ + c);
  w1 = *(const float4*)(vO + tf1 * C_ + c + 4);
  float pO1 = b0 * w0.x + b1 * w0.y + b2 * w0.z + b3 * w0.w +
              b4 * w1.x + b5 * w1.y + b6 * w1.z + b7 * w1.w;

#pragma unroll
  for (int off = 16; off > 0; off >>= 1) {
    pS0 += __shfl_xor(pS0, off);
    pO0 += __shfl_xor(pO0, off);
    pS1 += __shfl_xor(pS1, off);
    pO1 += __shfl_xor(pO1, off);
  }
  if (h == 0) {
    float sS = pS0 + abS[ti0];
    sS = sS > 0.f ? sS : 0.01f * sS;
    scoreS[e0] = sS;
    atomicAdd(&cnt[sn0 * R_ + ti0], 1);
    float sO = pO0 + abO[tf0];
    sO = sO > 0.f ? sO : 0.01f * sO;
    scoreO[e0] = sO;
    atomicAdd(&cnt[NKEY + dn0 * R_ + tf0], 1);

    sS = pS1 + abS[ti1];
    sS = sS > 0.f ? sS : 0.01f * sS;
    scoreS[e1] = sS;
    atomicAdd(&cnt[sn1 * R_ + ti1], 1);
    sO = pO1 + abO[tf1];
    sO = sO > 0.f ? sO : 0.01f * sO;
    scoreO[e1] = sO;
    atomicAdd(&cnt[NKEY + dn1 * R_ + tf1], 1);
  }
}

__global__ __launch_bounds__(256) void div_kernel(const int* __restrict__ cnt,
                                                  float* __restrict__ divS,
                                                  float* __restrict__ divO) {
  int n = blockIdx.x * 256 + threadIdx.x;
  int ds = 0, dq = 0;
#pragma unroll
  for (int r = 0; r < R_; ++r) {
    ds += (cnt[n * R_ + r] > 0);
    dq += (cnt[NKEY + n * R_ + r] > 0);
  }
  divS[n] = ds ? 1.f / (float)ds : 1.f;
  divO[n] = dq ? 1.f / (float)dq : 1.f;
}

// ---------------------------------------------------------------------------
// merged hierarchical exclusive scan over NKEY2=294912 counts (288 x 1024)
// ---------------------------------------------------------------------------
__global__ __launch_bounds__(256) void scan1_kernel(const int* __restrict__ cnt,
                                                    int* __restrict__ offs,
                                                    int* __restrict__ part) {
  __shared__ int lds[256];
  int b = blockIdx.x, t = threadIdx.x;
  int base = b * 1024 + t * 4;
  int4 v = *(const int4*)(cnt + base);
  int tsum = v.x + v.y + v.z + v.w;
  lds[t] = tsum;
  __syncthreads();
  for (int d = 1; d < 256; d <<= 1) {
    int x = (t >= d) ? lds[t - d] : 0;
    __syncthreads();
    lds[t] += x;
    __syncthreads();
  }
  int run = (t == 0) ? 0 : lds[t - 1];
  int4 o;
  o.x = run;
  o.y = run + v.x;
  o.z = o.y + v.y;
  o.w = o.z + v.z;
  *(int4*)(offs + base) = o;
  if (t == 255) part[b] = lds[255];
}

__global__ __launch_bounds__(512) void scan2_kernel(int* __restrict__ part) {
  __shared__ int lds[512];
  int t = threadIdx.x;
  lds[t] = (t < 288) ? part[t] : 0;
  __syncthreads();
  for (int d = 1; d < 512; d <<= 1) {
    int x = (t >= d) ? lds[t - d] : 0;
    __syncthreads();
    lds[t] += x;
    __syncthreads();
  }
  if (t < 288) part[t] = (t == 0) ? 0 : lds[t - 1];
}

__global__ __launch_bounds__(256) void scan3_kernel(const int* __restrict__ part,
                                                    int* __restrict__ offs,
                                                    int* __restrict__ cursor) {
  int i = blockIdx.x * 256 + threadIdx.x;  // grid 1152
  int v = offs[i] + part[i >> 10];
  offs[i] = v;
  cursor[i] = v;
}

// one pass: scatter edge into both branches' key lists
__global__ __launch_bounds__(256) void scatter_kernel(
    const int* __restrict__ et, const int* __restrict__ eti,
    const int* __restrict__ src, const int* __restrict__ dst,
    int* __restrict__ cursor, int* __restrict__ order) {
  int e = blockIdx.x * 256 + threadIdx.x;
  int kS = src[e] * R_ + eti[e];
  int kO = NKEY + dst[e] * R_ + et[e];
  order[atomicAdd(&cursor[kS], 1)] = e;
  order[atomicAdd(&cursor[kO], 1)] = e;
}

// ---------------------------------------------------------------------------
// zgather: 4 keys per wave. All len/offs loads, then all 4 order loads, then
// all 4 score gathers issued as independent batches before any compute
// -> ~4x memory-level parallelism. Arithmetic identical to the R2 version.
// ---------------------------------------------------------------------------
__device__ __forceinline__ void zkey_process(
    const float* __restrict__ rel, const float* __restrict__ score,
    const int* __restrict__ order, int len, int sta, int eL, float scL,
    int lane, int c, u16* __restrict__ z, int k2) {
  float ax = 0.f, ay = 0.f, az = 0.f, aw = 0.f;
  if (len == 1) {
    int e = __shfl(eL, 0);
    float4 x = *(const float4*)(rel + (long)e * C_ + c);
    ax = x.x; ay = x.y; az = x.z; aw = x.w;
  } else if (len > 1 && len <= 64) {
    float ex = (lane < len) ? __expf(scL) : 0.f;
    float den = ex;
#pragma unroll
    for (int off = 32; off > 0; off >>= 1) den += __shfl_xor(den, off);
    float inv = 1.f / den;
    int i = 0;
    for (; i + 2 <= len; i += 2) {
      int e0 = __shfl(eL, i);
      int e1 = __shfl(eL, i + 1);
      float a0 = __shfl(ex, i) * inv;
      float a1 = __shfl(ex, i + 1) * inv;
      float4 x0 = *(const float4*)(rel + (long)e0 * C_ + c);
      float4 x1 = *(const float4*)(rel + (long)e1 * C_ + c);
      ax += a0 * x0.x + a1 * x1.x;
      ay += a0 * x0.y + a1 * x1.y;
      az += a0 * x0.z + a1 * x1.z;
      aw += a0 * x0.w + a1 * x1.w;
    }
    if (i < len) {
      int e0 = __shfl(eL, i);
      float a0 = __shfl(ex, i) * inv;
      float4 x0 = *(const float4*)(rel + (long)e0 * C_ + c);
      ax += a0 * x0.x;
      ay += a0 * x0.y;
      az += a0 * x0.z;
      aw += a0 * x0.w;
    }
  } else if (len > 64) {
    float den = 0.f;
    for (int i = 0; i < len; ++i) {
      int e = order[sta + i];
      float ex2 = __expf(score[e]);
      den += ex2;
      float4 x = *(const float4*)(rel + (long)e * C_ + c);
      ax += ex2 * x.x; ay += ex2 * x.y; az += ex2 * x.z; aw += ex2 * x.w;
    }
    float inv = 1.f / den;
    ax *= inv; ay *= inv; az *= inv; aw *= inv;
  }
  int n = k2 / R_, r = k2 - n * R_;
  ushort4 hv;
  hv.x = f2bf(ax); hv.y = f2bf(ay); hv.z = f2bf(az); hv.w = f2bf(aw);
  *(ushort4*)(z + (long)n * (R_ * C_) + r * C_ + c) = hv;
}

__global__ __launch_bounds__(256) void zgather_kernel(
    const float* __restrict__ rel, const float* __restrict__ scoreS,
    const float* __restrict__ scoreO, const int* __restrict__ order,
    const int* __restrict__ offs, const int* __restrict__ cnt,
    u16* __restrict__ zS, u16* __restrict__ zO) {
  int wid = threadIdx.x >> 6;
  int lane = threadIdx.x & 63;
  int c = lane * 4;
  int key0 = (blockIdx.x * 4 + wid) * 4;  // NKEY % 4 == 0 -> no branch straddle
  const float* score = scoreS;
  u16* z = zS;
  int kb = key0;
  if (key0 >= NKEY) { score = scoreO; z = zO; kb = key0 - NKEY; }

  // phase 1: all lens/starts
  int len0 = cnt[key0], len1 = cnt[key0 + 1], len2 = cnt[key0 + 2], len3 = cnt[key0 + 3];
  int sta0 = offs[key0], sta1 = offs[key0 + 1], sta2 = offs[key0 + 2], sta3 = offs[key0 + 3];

  // phase 2: all order loads (independent)
  int e0 = 0, e1 = 0, e2 = 0, e3 = 0;
  if (len0 <= 64 && lane < len0) e0 = order[sta0 + lane];
  if (len1 <= 64 && lane < len1) e1 = order[sta1 + lane];
  if (len2 <= 64 && lane < len2) e2 = order[sta2 + lane];
  if (len3 <= 64 && lane < len3) e3 = order[sta3 + lane];

  // phase 3: all score gathers (4 independent chains)
  float s0 = 0.f, s1 = 0.f, s2 = 0.f, s3 = 0.f;
  if (len0 > 1 && len0 <= 64 && lane < len0) s0 = score[e0];
  if (len1 > 1 && len1 <= 64 && lane < len1) s1 = score[e1];
  if (len2 > 1 && len2 <= 64 && lane < len2) s2 = score[e2];
  if (len3 > 1 && len3 <= 64 && lane < len3) s3 = score[e3];

  // phase 4: process + store
  zkey_process(rel, score, order, len0, sta0, e0, s0, lane, c, z, kb + 0);
  zkey_process(rel, score, order, len1, sta1, e1, s1, lane, c, z, kb + 1);
  zkey_process(rel, score, order, len2, sta2, e2, s2, lane, c, z, kb + 2);
  zkey_process(rel, score, order, len3, sta3, e3, s3, lane, c, z, kb + 3);
}

// ---------------------------------------------------------------------------
extern "C" void kernel_launch(void* const* d_in, const int* in_sizes, int n_in,
                              void* d_out, int out_size, void* d_ws, size_t ws_size,
                              hipStream_t stream) {
  const int* edge_index = (const int*)d_in[0];
  const float* nf = (const float*)d_in[1];
  const float* ef = (const float*)d_in[2];
  const int* et = (const int*)d_in[3];
  const int* eti = (const int*)d_in[4];
  const float* s2r_basis = (const float*)d_in[6];
  const float* s2r_att = (const float*)d_in[7];
  const float* o2r_basis = (const float*)d_in[8];
  const float* o2r_att = (const float*)d_in[9];
  const float* r2s_basis = (const float*)d_in[10];
  const float* r2s_att = (const float*)d_in[11];
  const float* r2s_aw = (const float*)d_in[12];
  const float* r2s_ab = (const float*)d_in[13];
  const float* r2o_basis = (const float*)d_in[14];
  const float* r2o_att = (const float*)d_in[15];
  const float* r2o_aw = (const float*)d_in[16];
  const float* r2o_ab = (const float*)d_in[17];

  const int* src = edge_index;
  const int* dst = edge_index + E_;

  char* ws = (char*)d_ws;
  u16* WtSub = (u16*)(ws + 0);             // 1179648
  u16* WtObj = (u16*)(ws + 1179648);
  u16* WtR2S = (u16*)(ws + 2359296);
  u16* WtR2O = (u16*)(ws + 3538944);
  float* vS = (float*)(ws + 4718592);      // 9216
  float* vO = (float*)(ws + 4727808);
  u16* nfb = (u16*)(ws + 4737024);         // 8 MB -> 13125632
  float* scoreS = (float*)(ws + 13125632);
  float* scoreO = (float*)(ws + 14174208);
  int* cnt = (int*)(ws + 15222784);        // 2*NKEY ints -> 16402432
  int* offs = (int*)(ws + 16402432);       // -> 17582080
  int* cursor = (int*)(ws + 17582080);     // -> 18761728
  int* order = (int*)(ws + 18761728);      // 2E ints -> 20858880
  int* part = (int*)(ws + 20858880);       // -> 20860928
  float* divS = (float*)(ws + 20860928);   // -> 20926464
  float* divO = (float*)(ws + 20926464);   // -> 20992000
  u16* Ysub = (u16*)(ws + 20992000);       // 75.5 MB -> 96489472
  u16* Yobj = (u16*)(ws + 96489472);       // 75.5 MB -> 171986944
  u16* zS = Ysub;  // dead after relemb
  u16* zO = Yobj;  // dead after relemb

  float* node_out = (float*)d_out;
  float* rel_out = (float*)d_out + (long)N_ * C_;

  // ---- prep (one launch) ----
  prep_kernel<<<dim3(C_, R_), 256, 0, stream>>>(
      s2r_basis, s2r_att, o2r_basis, o2r_att,
      r2s_basis, r2s_att, r2s_aw, r2o_basis, r2o_att, r2o_aw,
      WtSub, WtObj, WtR2S, WtR2O, vS, vO);
  cvt_bf16_kernel<<<(N_ * C_) / 1024, 256, 0, stream>>>(nf, nfb);
  (void)hipMemsetAsync(cnt, 0, (size_t)NKEY2 * 4, stream);

  // ---- fused Y GEMM: z<9 -> Ysub, z>=9 -> Yobj ----
  gemmY_kernel<<<dim3(N_ / BM, C_ / BN, 2 * R_), 256, 0, stream>>>(
      nfb, C_, WtSub, WtObj, (long)C_ * C_, C_, Ysub, Yobj, (long)N_ * C_, C_);

  // ---- rel_emb + scores + merged histogram ----
  relemb_kernel<<<E_ / 16, 256, 0, stream>>>(ef, Ysub, Yobj, src, dst, et, eti,
                                             vS, r2s_ab, vO, r2o_ab, rel_out,
                                             scoreS, scoreO, cnt);
  div_kernel<<<N_ / 256, 256, 0, stream>>>(cnt, divS, divO);

  // ---- merged scan + scatter + zgather (both branches) ----
  scan1_kernel<<<288, 256, 0, stream>>>(cnt, offs, part);
  scan2_kernel<<<1, 512, 0, stream>>>(part);
  scan3_kernel<<<NKEY2 / 256, 256, 0, stream>>>(part, offs, cursor);
  scatter_kernel<<<E_ / 256, 256, 0, stream>>>(et, eti, src, dst, cursor, order);
  zgather_kernel<<<NKEY2 / 16, 256, 0, stream>>>(rel_out, scoreS, scoreO, order,
                                                 offs, cnt, zS, zO);

  // ---- fused agg GEMM (both branches + final epilogue) ----
  gemmAgg_kernel<<<dim3(N_ / 64, C_ / BN), 256, 0, stream>>>(
      zS, zO, WtR2S, WtR2O, node_out, nf, divS, divO);

  (void)in_sizes; (void)n_in; (void)out_size; (void)ws_size;
}

// Round 6
// 879.003 us; speedup vs baseline: 1.0621x; 1.0330x over previous
//
#include <hip/hip_runtime.h>

#define N_ 16384
#define E_ 262144
#define C_ 256
#define R_ 9
#define B_ 4
#define NKEY (N_ * R_)    // 147456
#define NKEY2 (2 * NKEY)  // 294912

typedef unsigned short u16;
typedef unsigned int u32;

typedef __bf16 bf16x8 __attribute__((ext_vector_type(8)));
typedef float f32x4 __attribute__((ext_vector_type(4)));

__device__ __forceinline__ u16 f2bf(float x) {
  u32 u = __float_as_uint(x);
  u32 r = (u + 0x7fffu + ((u >> 16) & 1u)) >> 16;  // RNE
  return (u16)r;
}
__device__ __forceinline__ float bf2f(u16 h) {
  return __uint_as_float(((u32)h) << 16);
}

// async global->LDS, 16B per lane
__device__ __forceinline__ void gld16(const void* g, void* l) {
  __builtin_amdgcn_global_load_lds(
      (const __attribute__((address_space(1))) void*)g,
      (__attribute__((address_space(3))) void*)l, 16, 0, 0);
}

// ---------------------------------------------------------------------------
// merged prep: all four W^T matrices + both v vectors in one launch
// ---------------------------------------------------------------------------
__global__ __launch_bounds__(256) void prep_kernel(
    const float* __restrict__ b1, const float* __restrict__ a1,
    const float* __restrict__ b2, const float* __restrict__ a2,
    const float* __restrict__ b3, const float* __restrict__ a3,
    const float* __restrict__ aw3,
    const float* __restrict__ b4, const float* __restrict__ a4,
    const float* __restrict__ aw4,
    u16* __restrict__ W1, u16* __restrict__ W2,
    u16* __restrict__ W3, u16* __restrict__ W4,
    float* __restrict__ v3, float* __restrict__ v4) {
  int c = blockIdx.x, r = blockIdx.y, o = threadIdx.x;
  float s1 = 0.f, s2 = 0.f, s3 = 0.f, s4 = 0.f;
#pragma unroll
  for (int b = 0; b < B_; ++b) {
    long bi = ((long)b * C_ + c) * C_ + o;
    s1 += a1[r * B_ + b] * b1[bi];
    s2 += a2[r * B_ + b] * b2[bi];
    s3 += a3[r * B_ + b] * b3[bi];
    s4 += a4[r * B_ + b] * b4[bi];
  }
  W1[((long)r * C_ + o) * C_ + c] = f2bf(s1);
  W2[((long)r * C_ + o) * C_ + c] = f2bf(s2);
  W3[(long)o * (R_ * C_) + r * C_ + c] = f2bf(s3);
  W4[(long)o * (R_ * C_) + r * C_ + c] = f2bf(s4);

  __shared__ float red[256];
  red[o] = s3 * aw3[r * C_ + o];
  __syncthreads();
  for (int s = 128; s > 0; s >>= 1) {
    if (o < s) red[o] += red[o + s];
    __syncthreads();
  }
  float rv3 = red[0];
  __syncthreads();
  red[o] = s4 * aw4[r * C_ + o];
  __syncthreads();
  for (int s = 128; s > 0; s >>= 1) {
    if (o < s) red[o] += red[o + s];
    __syncthreads();
  }
  if (o == 0) {
    v3[r * C_ + c] = rv3;
    v4[r * C_ + c] = red[0];
  }
}

__global__ void cvt_bf16_kernel(const float* __restrict__ in, u16* __restrict__ out) {
  long i = ((long)blockIdx.x * 256 + threadIdx.x) * 4;
  float4 f = *(const float4*)(in + i);
  ushort4 h;
  h.x = f2bf(f.x); h.y = f2bf(f.y); h.z = f2bf(f.z); h.w = f2bf(f.w);
  *(ushort4*)(out + i) = h;
}

// ---------------------------------------------------------------------------
// Fused Y GEMM 128x128x32: z<R uses (Bt0,Out0), else (Bt1,Out1). bf16 out.
// ---------------------------------------------------------------------------
#define BM 128
#define BN 128
#define BK 32

__global__ __launch_bounds__(256) void gemmY_kernel(
    const u16* __restrict__ A, int lda,
    const u16* __restrict__ Bt0, const u16* __restrict__ Bt1, long bBatch, int K,
    u16* __restrict__ Out0, u16* __restrict__ Out1, long cBatch, int ldc) {
  __shared__ __attribute__((aligned(16))) u16 As[BM * BK];
  __shared__ __attribute__((aligned(16))) u16 Bs[BN * BK];

  const int t = threadIdx.x;
  const int m0 = blockIdx.x * BM;
  const int n0 = blockIdx.y * BN;
  const int zb = blockIdx.z;
  const long z = (zb < R_) ? zb : zb - R_;
  const u16* Bt = (zb < R_) ? Bt0 : Bt1;
  u16* Out = (zb < R_) ? Out0 : Out1;

  const int sr = t >> 2;
  const int sk = (t & 3) * 8;

  const int w = t >> 6, lane = t & 63;
  const int wm = (w >> 1) * 64, wn = (w & 1) * 64;
  const int lr = lane & 15;
  const int lk = (lane >> 4) * 8;

  f32x4 acc[4][4];
#pragma unroll
  for (int i = 0; i < 4; ++i)
#pragma unroll
    for (int j = 0; j < 4; ++j) acc[i][j] = (f32x4){0.f, 0.f, 0.f, 0.f};

  const u16* aR = A + (long)(m0 + sr) * lda + sk;
  const u16* bR = Bt + z * bBatch + (long)(n0 + sr) * K + sk;
  const long aStep = 64L * lda;
  const long bStep = 64L * K;

  u16* aD0 = &As[t * 8];
  u16* aD1 = &As[2048 + t * 8];
  u16* bD0 = &Bs[t * 8];
  u16* bD1 = &Bs[2048 + t * 8];

  for (int k0 = 0; k0 < K; k0 += BK) {
    gld16(aR, aD0);
    gld16(aR + aStep, aD1);
    gld16(bR, bD0);
    gld16(bR + bStep, bD1);
    aR += BK;
    bR += BK;
    __syncthreads();

    bf16x8 af[4], bg[4];
#pragma unroll
    for (int mi = 0; mi < 4; ++mi)
      af[mi] = *(const bf16x8*)&As[(wm + mi * 16 + lr) * BK + lk];
#pragma unroll
    for (int ni = 0; ni < 4; ++ni)
      bg[ni] = *(const bf16x8*)&Bs[(wn + ni * 16 + lr) * BK + lk];
#pragma unroll
    for (int mi = 0; mi < 4; ++mi)
#pragma unroll
      for (int ni = 0; ni < 4; ++ni)
        acc[mi][ni] = __builtin_amdgcn_mfma_f32_16x16x32_bf16(af[mi], bg[ni], acc[mi][ni], 0, 0, 0);

    __syncthreads();
  }

  long base = z * cBatch;
#pragma unroll
  for (int mi = 0; mi < 4; ++mi) {
    int rowb = m0 + wm + mi * 16 + ((lane >> 4) * 4);
#pragma unroll
    for (int ni = 0; ni < 4; ++ni) {
      int col = n0 + wn + ni * 16 + lr;
      f32x4 c = acc[mi][ni];
#pragma unroll
      for (int i = 0; i < 4; ++i) {
        long idx = base + (long)(rowb + i) * ldc + col;
        Out[idx] = f2bf(c[i]);
      }
    }
  }
}

// ---------------------------------------------------------------------------
// Fused agg GEMM: both branches (K=2304 each) + final epilogue in one kernel.
// BM=64, BN=128. Grid is (n, m) so both n-tiles of an m-row run back-to-back
// -> the 294KB A panel is L2/L3-hit for the second block (saves ~150MB HBM).
// node = nf + 0.5*(divS*accS + divO*accO)
// ---------------------------------------------------------------------------
__global__ __launch_bounds__(256) void gemmAgg_kernel(
    const u16* __restrict__ AS, const u16* __restrict__ AO,
    const u16* __restrict__ BtS, const u16* __restrict__ BtO,
    float* __restrict__ Out,
    const float* __restrict__ nf,
    const float* __restrict__ divS, const float* __restrict__ divO) {
  const int K = R_ * C_;  // 2304
  __shared__ __attribute__((aligned(16))) u16 As[64 * BK];
  __shared__ __attribute__((aligned(16))) u16 Bs[BN * BK];

  const int t = threadIdx.x;
  const int m0 = blockIdx.y * 64;
  const int n0 = blockIdx.x * BN;

  const int sr = t >> 2;
  const int sk = (t & 3) * 8;

  const int w = t >> 6, lane = t & 63;
  const int wm = (w >> 1) * 32, wn = (w & 1) * 64;
  const int lr = lane & 15;
  const int lk = (lane >> 4) * 8;

  u16* aD = &As[t * 8];
  u16* bD0 = &Bs[t * 8];
  u16* bD1 = &Bs[2048 + t * 8];
  const long bStep = 64L * K;

  f32x4 accS[2][4], accO[2][4];
#pragma unroll
  for (int i = 0; i < 2; ++i)
#pragma unroll
    for (int j = 0; j < 4; ++j) {
      accS[i][j] = (f32x4){0.f, 0.f, 0.f, 0.f};
      accO[i][j] = (f32x4){0.f, 0.f, 0.f, 0.f};
    }

  // ---- pass S ----
  {
    const u16* aR = AS + (long)(m0 + sr) * K + sk;
    const u16* bR = BtS + (long)(n0 + sr) * K + sk;
    for (int k0 = 0; k0 < K; k0 += BK) {
      gld16(aR, aD);
      gld16(bR, bD0);
      gld16(bR + bStep, bD1);
      aR += BK;
      bR += BK;
      __syncthreads();
      bf16x8 af[2], bg[4];
#pragma unroll
      for (int mi = 0; mi < 2; ++mi)
        af[mi] = *(const bf16x8*)&As[(wm + mi * 16 + lr) * BK + lk];
#pragma unroll
      for (int ni = 0; ni < 4; ++ni)
        bg[ni] = *(const bf16x8*)&Bs[(wn + ni * 16 + lr) * BK + lk];
#pragma unroll
      for (int mi = 0; mi < 2; ++mi)
#pragma unroll
        for (int ni = 0; ni < 4; ++ni)
          accS[mi][ni] = __builtin_amdgcn_mfma_f32_16x16x32_bf16(af[mi], bg[ni], accS[mi][ni], 0, 0, 0);
      __syncthreads();
    }
  }
  // ---- pass O ----
  {
    const u16* aR = AO + (long)(m0 + sr) * K + sk;
    const u16* bR = BtO + (long)(n0 + sr) * K + sk;
    for (int k0 = 0; k0 < K; k0 += BK) {
      gld16(aR, aD);
      gld16(bR, bD0);
      gld16(bR + bStep, bD1);
      aR += BK;
      bR += BK;
      __syncthreads();
      bf16x8 af[2], bg[4];
#pragma unroll
      for (int mi = 0; mi < 2; ++mi)
        af[mi] = *(const bf16x8*)&As[(wm + mi * 16 + lr) * BK + lk];
#pragma unroll
      for (int ni = 0; ni < 4; ++ni)
        bg[ni] = *(const bf16x8*)&Bs[(wn + ni * 16 + lr) * BK + lk];
#pragma unroll
      for (int mi = 0; mi < 2; ++mi)
#pragma unroll
        for (int ni = 0; ni < 4; ++ni)
          accO[mi][ni] = __builtin_amdgcn_mfma_f32_16x16x32_bf16(af[mi], bg[ni], accO[mi][ni], 0, 0, 0);
      __syncthreads();
    }
  }

#pragma unroll
  for (int mi = 0; mi < 2; ++mi) {
    int rowb = m0 + wm + mi * 16 + ((lane >> 4) * 4);
    float fsS[4], fsO[4];
#pragma unroll
    for (int i = 0; i < 4; ++i) {
      fsS[i] = 0.5f * divS[rowb + i];
      fsO[i] = 0.5f * divO[rowb + i];
    }
#pragma unroll
    for (int ni = 0; ni < 4; ++ni) {
      int col = n0 + wn + ni * 16 + lr;
      f32x4 cS = accS[mi][ni];
      f32x4 cO = accO[mi][ni];
#pragma unroll
      for (int i = 0; i < 4; ++i) {
        long idx = (long)(rowb + i) * C_ + col;
        Out[idx] = nf[idx] + fsS[i] * cS[i] + fsO[i] * cO[i];
      }
    }
  }
}

// ---------------------------------------------------------------------------
// rel_emb + fused scores + merged histogram.
// TWO edges per 64-lane wave, 4 ch/lane (low footprint: ~32 VGPR for high
// occupancy) with all long-latency loads issued before compute (2x MLP).
// Also writes a bf16 copy of rel (relB, 134MB = L3-resident) for zgather.
// ---------------------------------------------------------------------------
__global__ __launch_bounds__(256) void relemb_kernel(
    const float* __restrict__ ef, const u16* __restrict__ Ysub,
    const u16* __restrict__ Yobj, const int* __restrict__ src,
    const int* __restrict__ dst, const int* __restrict__ et,
    const int* __restrict__ eti, const float* __restrict__ vS,
    const float* __restrict__ abS, const float* __restrict__ vO,
    const float* __restrict__ abO, float* __restrict__ rel,
    u16* __restrict__ relB,
    float* __restrict__ scoreS, float* __restrict__ scoreO,
    int* __restrict__ cnt) {
  int wv = threadIdx.x >> 6;
  int lane = threadIdx.x & 63;
  int c = lane * 4;
  int e0 = blockIdx.x * 8 + wv * 2;
  int e1 = e0 + 1;

  int sn0 = src[e0], dn0 = dst[e0], tf0 = et[e0], ti0 = eti[e0];
  int sn1 = src[e1], dn1 = dst[e1], tf1 = et[e1], ti1 = eti[e1];

  ushort4 ys0 = *(const ushort4*)(Ysub + ((long)tf0 * N_ + sn0) * C_ + c);
  ushort4 yo0 = *(const ushort4*)(Yobj + ((long)ti0 * N_ + dn0) * C_ + c);
  ushort4 ys1 = *(const ushort4*)(Ysub + ((long)tf1 * N_ + sn1) * C_ + c);
  ushort4 yo1 = *(const ushort4*)(Yobj + ((long)ti1 * N_ + dn1) * C_ + c);

  long ei0 = (long)e0 * C_ + c;
  long ei1 = (long)e1 * C_ + c;
  float4 f0 = *(const float4*)(ef + ei0);
  float4 f1 = *(const float4*)(ef + ei1);

  float a0 = f0.x + 0.5f * (bf2f(ys0.x) + bf2f(yo0.x));
  float a1 = f0.y + 0.5f * (bf2f(ys0.y) + bf2f(yo0.y));
  float a2 = f0.z + 0.5f * (bf2f(ys0.z) + bf2f(yo0.z));
  float a3 = f0.w + 0.5f * (bf2f(ys0.w) + bf2f(yo0.w));
  float b0 = f1.x + 0.5f * (bf2f(ys1.x) + bf2f(yo1.x));
  float b1 = f1.y + 0.5f * (bf2f(ys1.y) + bf2f(yo1.y));
  float b2 = f1.z + 0.5f * (bf2f(ys1.z) + bf2f(yo1.z));
  float b3 = f1.w + 0.5f * (bf2f(ys1.w) + bf2f(yo1.w));

  *(float4*)(rel + ei0) = (float4){a0, a1, a2, a3};
  *(float4*)(rel + ei1) = (float4){b0, b1, b2, b3};
  ushort4 h0, h1;
  h0.x = f2bf(a0); h0.y = f2bf(a1); h0.z = f2bf(a2); h0.w = f2bf(a3);
  h1.x = f2bf(b0); h1.y = f2bf(b1); h1.z = f2bf(b2); h1.w = f2bf(b3);
  *(ushort4*)(relB + ei0) = h0;
  *(ushort4*)(relB + ei1) = h1;

  // dots (v tables 9KB each: L1/L2-resident)
  float4 w;
  w = *(const float4*)(vS + ti0 * C_ + c);
  float pS0 = a0 * w.x + a1 * w.y + a2 * w.z + a3 * w.w;
  w = *(const float4*)(vO + tf0 * C_ + c);
  float pO0 = a0 * w.x + a1 * w.y + a2 * w.z + a3 * w.w;
  w = *(const float4*)(vS + ti1 * C_ + c);
  float pS1 = b0 * w.x + b1 * w.y + b2 * w.z + b3 * w.w;
  w = *(const float4*)(vO + tf1 * C_ + c);
  float pO1 = b0 * w.x + b1 * w.y + b2 * w.z + b3 * w.w;

#pragma unroll
  for (int off = 32; off > 0; off >>= 1) {
    pS0 += __shfl_xor(pS0, off);
    pO0 += __shfl_xor(pO0, off);
    pS1 += __shfl_xor(pS1, off);
    pO1 += __shfl_xor(pO1, off);
  }
  if (lane == 0) {
    float sS = pS0 + abS[ti0];
    sS = sS > 0.f ? sS : 0.01f * sS;
    scoreS[e0] = sS;
    atomicAdd(&cnt[sn0 * R_ + ti0], 1);
    float sO = pO0 + abO[tf0];
    sO = sO > 0.f ? sO : 0.01f * sO;
    scoreO[e0] = sO;
    atomicAdd(&cnt[NKEY + dn0 * R_ + tf0], 1);

    sS = pS1 + abS[ti1];
    sS = sS > 0.f ? sS : 0.01f * sS;
    scoreS[e1] = sS;
    atomicAdd(&cnt[sn1 * R_ + ti1], 1);
    sO = pO1 + abO[tf1];
    sO = sO > 0.f ? sO : 0.01f * sO;
    scoreO[e1] = sO;
    atomicAdd(&cnt[NKEY + dn1 * R_ + tf1], 1);
  }
}

__global__ __launch_bounds__(256) void div_kernel(const int* __restrict__ cnt,
                                                  float* __restrict__ divS,
                                                  float* __restrict__ divO) {
  int n = blockIdx.x * 256 + threadIdx.x;
  int ds = 0, dq = 0;
#pragma unroll
  for (int r = 0; r < R_; ++r) {
    ds += (cnt[n * R_ + r] > 0);
    dq += (cnt[NKEY + n * R_ + r] > 0);
  }
  divS[n] = ds ? 1.f / (float)ds : 1.f;
  divO[n] = dq ? 1.f / (float)dq : 1.f;
}

// ---------------------------------------------------------------------------
// merged hierarchical exclusive scan over NKEY2=294912 counts (288 x 1024)
// ---------------------------------------------------------------------------
__global__ __launch_bounds__(256) void scan1_kernel(const int* __restrict__ cnt,
                                                    int* __restrict__ offs,
                                                    int* __restrict__ part) {
  __shared__ int lds[256];
  int b = blockIdx.x, t = threadIdx.x;
  int base = b * 1024 + t * 4;
  int4 v = *(const int4*)(cnt + base);
  int tsum = v.x + v.y + v.z + v.w;
  lds[t] = tsum;
  __syncthreads();
  for (int d = 1; d < 256; d <<= 1) {
    int x = (t >= d) ? lds[t - d] : 0;
    __syncthreads();
    lds[t] += x;
    __syncthreads();
  }
  int run = (t == 0) ? 0 : lds[t - 1];
  int4 o;
  o.x = run;
  o.y = run + v.x;
  o.z = o.y + v.y;
  o.w = o.z + v.z;
  *(int4*)(offs + base) = o;
  if (t == 255) part[b] = lds[255];
}

__global__ __launch_bounds__(512) void scan2_kernel(int* __restrict__ part) {
  __shared__ int lds[512];
  int t = threadIdx.x;
  lds[t] = (t < 288) ? part[t] : 0;
  __syncthreads();
  for (int d = 1; d < 512; d <<= 1) {
    int x = (t >= d) ? lds[t - d] : 0;
    __syncthreads();
    lds[t] += x;
    __syncthreads();
  }
  if (t < 288) part[t] = (t == 0) ? 0 : lds[t - 1];
}

__global__ __launch_bounds__(256) void scan3_kernel(const int* __restrict__ part,
                                                    int* __restrict__ offs,
                                                    int* __restrict__ cursor) {
  int i = blockIdx.x * 256 + threadIdx.x;  // grid 1152
  int v = offs[i] + part[i >> 10];
  offs[i] = v;
  cursor[i] = v;
}

// one pass: scatter edge into both branches' key lists
__global__ __launch_bounds__(256) void scatter_kernel(
    const int* __restrict__ et, const int* __restrict__ eti,
    const int* __restrict__ src, const int* __restrict__ dst,
    int* __restrict__ cursor, int* __restrict__ order) {
  int e = blockIdx.x * 256 + threadIdx.x;
  int kS = src[e] * R_ + eti[e];
  int kO = NKEY + dst[e] * R_ + et[e];
  order[atomicAdd(&cursor[kS], 1)] = e;
  order[atomicAdd(&cursor[kO], 1)] = e;
}

// ---------------------------------------------------------------------------
// zgather: 4 keys per wave, batched independent loads; gathers read the bf16
// rel copy (L3-resident, half the bytes). len==1 path is bit-identical
// (f2bf(bf2f(x)) == x).
// ---------------------------------------------------------------------------
__device__ __forceinline__ void zkey_process(
    const u16* __restrict__ relB, const float* __restrict__ score,
    const int* __restrict__ order, int len, int sta, int eL, float scL,
    int lane, int c, u16* __restrict__ z, int k2) {
  float ax = 0.f, ay = 0.f, az = 0.f, aw = 0.f;
  ushort4 hv;
  if (len == 1) {
    int e = __shfl(eL, 0);
    hv = *(const ushort4*)(relB + (long)e * C_ + c);
  } else {
    if (len > 1 && len <= 64) {
      float ex = (lane < len) ? __expf(scL) : 0.f;
      float den = ex;
#pragma unroll
      for (int off = 32; off > 0; off >>= 1) den += __shfl_xor(den, off);
      float inv = 1.f / den;
      int i = 0;
      for (; i + 2 <= len; i += 2) {
        int e0 = __shfl(eL, i);
        int e1 = __shfl(eL, i + 1);
        float a0 = __shfl(ex, i) * inv;
        float a1 = __shfl(ex, i + 1) * inv;
        ushort4 x0 = *(const ushort4*)(relB + (long)e0 * C_ + c);
        ushort4 x1 = *(const ushort4*)(relB + (long)e1 * C_ + c);
        ax += a0 * bf2f(x0.x) + a1 * bf2f(x1.x);
        ay += a0 * bf2f(x0.y) + a1 * bf2f(x1.y);
        az += a0 * bf2f(x0.z) + a1 * bf2f(x1.z);
        aw += a0 * bf2f(x0.w) + a1 * bf2f(x1.w);
      }
      if (i < len) {
        int e0 = __shfl(eL, i);
        float a0 = __shfl(ex, i) * inv;
        ushort4 x0 = *(const ushort4*)(relB + (long)e0 * C_ + c);
        ax += a0 * bf2f(x0.x);
        ay += a0 * bf2f(x0.y);
        az += a0 * bf2f(x0.z);
        aw += a0 * bf2f(x0.w);
      }
    } else if (len > 64) {
      float den = 0.f;
      for (int i = 0; i < len; ++i) {
        int e = order[sta + i];
        float ex2 = __expf(score[e]);
        den += ex2;
        ushort4 x = *(const ushort4*)(relB + (long)e * C_ + c);
        ax += ex2 * bf2f(x.x); ay += ex2 * bf2f(x.y);
        az += ex2 * bf2f(x.z); aw += ex2 * bf2f(x.w);
      }
      float inv = 1.f / den;
      ax *= inv; ay *= inv; az *= inv; aw *= inv;
    }
    hv.x = f2bf(ax); hv.y = f2bf(ay); hv.z = f2bf(az); hv.w = f2bf(aw);
  }
  int n = k2 / R_, r = k2 - n * R_;
  *(ushort4*)(z + (long)n * (R_ * C_) + r * C_ + c) = hv;
}

__global__ __launch_bounds__(256) void zgather_kernel(
    const u16* __restrict__ relB, const float* __restrict__ scoreS,
    const float* __restrict__ scoreO, const int* __restrict__ order,
    const int* __restrict__ offs, const int* __restrict__ cnt,
    u16* __restrict__ zS, u16* __restrict__ zO) {
  int wid = threadIdx.x >> 6;
  int lane = threadIdx.x & 63;
  int c = lane * 4;
  int key0 = (blockIdx.x * 4 + wid) * 4;  // NKEY % 4 == 0 -> no branch straddle
  const float* score = scoreS;
  u16* z = zS;
  int kb = key0;
  if (key0 >= NKEY) { score = scoreO; z = zO; kb = key0 - NKEY; }

  // phase 1: all lens/starts
  int len0 = cnt[key0], len1 = cnt[key0 + 1], len2 = cnt[key0 + 2], len3 = cnt[key0 + 3];
  int sta0 = offs[key0], sta1 = offs[key0 + 1], sta2 = offs[key0 + 2], sta3 = offs[key0 + 3];

  // phase 2: all order loads (independent)
  int e0 = 0, e1 = 0, e2 = 0, e3 = 0;
  if (len0 <= 64 && lane < len0) e0 = order[sta0 + lane];
  if (len1 <= 64 && lane < len1) e1 = order[sta1 + lane];
  if (len2 <= 64 && lane < len2) e2 = order[sta2 + lane];
  if (len3 <= 64 && lane < len3) e3 = order[sta3 + lane];

  // phase 3: all score gathers (independent)
  float s0 = 0.f, s1 = 0.f, s2 = 0.f, s3 = 0.f;
  if (len0 > 1 && len0 <= 64 && lane < len0) s0 = score[e0];
  if (len1 > 1 && len1 <= 64 && lane < len1) s1 = score[e1];
  if (len2 > 1 && len2 <= 64 && lane < len2) s2 = score[e2];
  if (len3 > 1 && len3 <= 64 && lane < len3) s3 = score[e3];

  // phase 4: process + store
  zkey_process(relB, score, order, len0, sta0, e0, s0, lane, c, z, kb + 0);
  zkey_process(relB, score, order, len1, sta1, e1, s1, lane, c, z, kb + 1);
  zkey_process(relB, score, order, len2, sta2, e2, s2, lane, c, z, kb + 2);
  zkey_process(relB, score, order, len3, sta3, e3, s3, lane, c, z, kb + 3);
}

// ---------------------------------------------------------------------------
extern "C" void kernel_launch(void* const* d_in, const int* in_sizes, int n_in,
                              void* d_out, int out_size, void* d_ws, size_t ws_size,
                              hipStream_t stream) {
  const int* edge_index = (const int*)d_in[0];
  const float* nf = (const float*)d_in[1];
  const float* ef = (const float*)d_in[2];
  const int* et = (const int*)d_in[3];
  const int* eti = (const int*)d_in[4];
  const float* s2r_basis = (const float*)d_in[6];
  const float* s2r_att = (const float*)d_in[7];
  const float* o2r_basis = (const float*)d_in[8];
  const float* o2r_att = (const float*)d_in[9];
  const float* r2s_basis = (const float*)d_in[10];
  const float* r2s_att = (const float*)d_in[11];
  const float* r2s_aw = (const float*)d_in[12];
  const float* r2s_ab = (const float*)d_in[13];
  const float* r2o_basis = (const float*)d_in[14];
  const float* r2o_att = (const float*)d_in[15];
  const float* r2o_aw = (const float*)d_in[16];
  const float* r2o_ab = (const float*)d_in[17];

  const int* src = edge_index;
  const int* dst = edge_index + E_;

  char* ws = (char*)d_ws;
  u16* WtSub = (u16*)(ws + 0);             // 1179648
  u16* WtObj = (u16*)(ws + 1179648);
  u16* WtR2S = (u16*)(ws + 2359296);
  u16* WtR2O = (u16*)(ws + 3538944);
  float* vS = (float*)(ws + 4718592);      // 9216
  float* vO = (float*)(ws + 4727808);
  u16* nfb = (u16*)(ws + 4737024);         // 8 MB -> 13125632
  float* scoreS = (float*)(ws + 13125632);
  float* scoreO = (float*)(ws + 14174208);
  int* cnt = (int*)(ws + 15222784);        // 2*NKEY ints -> 16402432
  int* offs = (int*)(ws + 16402432);       // -> 17582080
  int* cursor = (int*)(ws + 17582080);     // -> 18761728
  int* order = (int*)(ws + 18761728);      // 2E ints -> 20858880
  int* part = (int*)(ws + 20858880);       // -> 20860928
  float* divS = (float*)(ws + 20860928);   // -> 20926464
  float* divO = (float*)(ws + 20926464);   // -> 20992000
  u16* Ysub = (u16*)(ws + 20992000);       // 75.5 MB -> 96489472
  u16* Yobj = (u16*)(ws + 96489472);       // 75.5 MB -> 171986944
  u16* relB = (u16*)(ws + 171986944);      // 128 MB  -> 306204672
  u16* zS = Ysub;  // dead after relemb
  u16* zO = Yobj;  // dead after relemb

  float* node_out = (float*)d_out;
  float* rel_out = (float*)d_out + (long)N_ * C_;

  // ---- prep (one launch) ----
  prep_kernel<<<dim3(C_, R_), 256, 0, stream>>>(
      s2r_basis, s2r_att, o2r_basis, o2r_att,
      r2s_basis, r2s_att, r2s_aw, r2o_basis, r2o_att, r2o_aw,
      WtSub, WtObj, WtR2S, WtR2O, vS, vO);
  cvt_bf16_kernel<<<(N_ * C_) / 1024, 256, 0, stream>>>(nf, nfb);
  (void)hipMemsetAsync(cnt, 0, (size_t)NKEY2 * 4, stream);

  // ---- fused Y GEMM: z<9 -> Ysub, z>=9 -> Yobj ----
  gemmY_kernel<<<dim3(N_ / BM, C_ / BN, 2 * R_), 256, 0, stream>>>(
      nfb, C_, WtSub, WtObj, (long)C_ * C_, C_, Ysub, Yobj, (long)N_ * C_, C_);

  // ---- rel_emb + scores + merged histogram ----
  relemb_kernel<<<E_ / 8, 256, 0, stream>>>(ef, Ysub, Yobj, src, dst, et, eti,
                                            vS, r2s_ab, vO, r2o_ab, rel_out,
                                            relB, scoreS, scoreO, cnt);
  div_kernel<<<N_ / 256, 256, 0, stream>>>(cnt, divS, divO);

  // ---- merged scan + scatter + zgather (both branches) ----
  scan1_kernel<<<288, 256, 0, stream>>>(cnt, offs, part);
  scan2_kernel<<<1, 512, 0, stream>>>(part);
  scan3_kernel<<<NKEY2 / 256, 256, 0, stream>>>(part, offs, cursor);
  scatter_kernel<<<E_ / 256, 256, 0, stream>>>(et, eti, src, dst, cursor, order);
  zgather_kernel<<<NKEY2 / 16, 256, 0, stream>>>(relB, scoreS, scoreO, order,
                                                 offs, cnt, zS, zO);

  // ---- fused agg GEMM (both branches + final epilogue), n-fastest grid ----
  gemmAgg_kernel<<<dim3(C_ / BN, N_ / 64), 256, 0, stream>>>(
      zS, zO, WtR2S, WtR2O, node_out, nf, divS, divO);

  (void)in_sizes; (void)n_in; (void)out_size; (void)ws_size;
}